// Round 2
// 13547.043 us; speedup vs baseline: 2.6194x; 2.6194x over previous
//
#include <hip/hip_runtime.h>
#include <stdint.h>

typedef short bf16x8 __attribute__((ext_vector_type(8)));
typedef float f32x4 __attribute__((ext_vector_type(4)));
typedef unsigned short u16;
typedef unsigned long long u64;

__device__ __forceinline__ u16 f2bf(float f) {
    unsigned int u = __float_as_uint(f);
    u = (u + 0x7FFFu + ((u >> 16) & 1u)) >> 16;
    return (u16)u;
}
__device__ __forceinline__ float bf2f(u16 h) {
    return __uint_as_float(((unsigned int)h) << 16);
}
__device__ __forceinline__ float sigm(float x) { return 1.f / (1.f + __expf(-x)); }
__device__ __forceinline__ float tanh_fast(float x) {
    return 1.f - 2.f / (__expf(2.f * x) + 1.f);
}
// nonzero iff any u16 half of x equals the 0x7F7F sentinel (|h|<1 => unreachable)
__device__ __forceinline__ unsigned bad16(unsigned x) {
    x ^= 0x7F7F7F7Fu;
    return (x - 0x00010001u) & ~x & 0x80008000u;
}
__device__ __forceinline__ unsigned bad64(u64 x) {
    return bad16((unsigned)x) | bad16((unsigned)(x >> 32));
}

// ---------------------------------------------------------------------------
// K0: transpose fp32 [1024][4096] weight -> bf16 [4096][1024] (K-contiguous)
// ---------------------------------------------------------------------------
__global__ void transpose_w(const float* __restrict__ src, u16* __restrict__ dst)
{
    __shared__ float tile[32][33];
    const int gx = blockIdx.x;   // over 4096/32
    const int gy = blockIdx.y;   // over 1024/32
    const int tx = threadIdx.x;  // 0..31
    const int ty = threadIdx.y;  // 0..7
    #pragma unroll
    for (int i = 0; i < 4; ++i) {
        const int row = gy * 32 + ty + i * 8;
        tile[ty + i * 8][tx] = src[(size_t)row * 4096 + gx * 32 + tx];
    }
    __syncthreads();
    #pragma unroll
    for (int i = 0; i < 4; ++i) {
        const int row = gx * 32 + ty + i * 8;
        dst[(size_t)row * 1024 + gy * 32 + tx] = f2bf(tile[tx][ty + i * 8]);
    }
}

// ---------------------------------------------------------------------------
// K1: convert input chunk fp32 [B][T][D] -> bf16 rows r = t_local*32 + b
// ---------------------------------------------------------------------------
__global__ void convert_inputs(const float* __restrict__ in, u16* __restrict__ A, const int t0)
{
    const int r = blockIdx.x;          // t*32 + b
    const int t = r >> 5, b = r & 31;
    const int d = threadIdx.x << 2;
    const float4 v = *(const float4*)(in + ((size_t)b * 2048 + t0 + t) * 1024 + d);
    ushort4 o = make_ushort4(f2bf(v.x), f2bf(v.y), f2bf(v.z), f2bf(v.w));
    *(ushort4*)(A + (size_t)r * 1024 + d) = o;
}

// ---------------------------------------------------------------------------
// K2: xw2[t][w][q][eu][eb] = sum_k A[r][k] * WiT[g][k] + bias[g]  (bf16)
// 128x128 tile, BK=32, 4 waves each 64x64, mfma 16x16x32 bf16
// ---------------------------------------------------------------------------
__launch_bounds__(256)
__global__ void gemm_xw(const u16* __restrict__ A, const u16* __restrict__ B,
                        const float* __restrict__ bias, u16* __restrict__ C)
{
    __shared__ u16 As[128 * 32];
    __shared__ u16 Bs[128 * 32];
    const int bm = blockIdx.x >> 5;
    const int bn = blockIdx.x & 31;
    const int tid = threadIdx.x;
    const int wave = tid >> 6, lane = tid & 63;
    const int wr = wave >> 1, wc = wave & 1;
    const int c16 = lane & 15, quad = lane >> 4;

    f32x4 acc[4][4];
    #pragma unroll
    for (int i = 0; i < 4; ++i)
        #pragma unroll
        for (int j = 0; j < 4; ++j) acc[i][j] = (f32x4){0.f, 0.f, 0.f, 0.f};

    const int srow = tid >> 1;
    const int scol = (tid & 1) << 4;
    const u16* Ag = A + (size_t)(bm * 128 + srow) * 1024 + scol;
    const u16* Bg = B + (size_t)(bn * 128 + srow) * 1024 + scol;
    uint4* AsW = (uint4*)(As + srow * 32 + scol);
    uint4* BsW = (uint4*)(Bs + srow * 32 + scol);

    for (int kt = 0; kt < 32; ++kt) {
        const uint4* ag = (const uint4*)(Ag + kt * 32);
        const uint4* bg = (const uint4*)(Bg + kt * 32);
        const uint4 a0 = ag[0], a1 = ag[1];
        const uint4 b0 = bg[0], b1 = bg[1];
        __syncthreads();
        AsW[0] = a0; AsW[1] = a1;
        BsW[0] = b0; BsW[1] = b1;
        __syncthreads();
        bf16x8 af[4], bfr[4];
        #pragma unroll
        for (int mt = 0; mt < 4; ++mt)
            af[mt] = *(const bf16x8*)(As + (wr * 64 + mt * 16 + c16) * 32 + quad * 8);
        #pragma unroll
        for (int nt = 0; nt < 4; ++nt)
            bfr[nt] = *(const bf16x8*)(Bs + (wc * 64 + nt * 16 + c16) * 32 + quad * 8);
        #pragma unroll
        for (int mt = 0; mt < 4; ++mt)
            #pragma unroll
            for (int nt = 0; nt < 4; ++nt)
                acc[mt][nt] = __builtin_amdgcn_mfma_f32_16x16x32_bf16(af[mt], bfr[nt], acc[mt][nt], 0, 0, 0);
    }
    #pragma unroll
    for (int nt = 0; nt < 4; ++nt) {
        const int g = bn * 128 + wc * 64 + nt * 16 + c16;
        const float bv = bias[g];
        const int q  = g >> 10;
        const int u  = g & 1023;
        const int w2 = u >> 2, eu = u & 3;
        #pragma unroll
        for (int mt = 0; mt < 4; ++mt) {
            const int r0 = bm * 128 + wr * 64 + mt * 16 + quad * 4;
            #pragma unroll
            for (int reg = 0; reg < 4; ++reg) {
                const int r = r0 + reg;
                const int t = r >> 5, b = r & 31;
                C[(size_t)(t * 256 + w2) * 512 + q * 128 + eu * 32 + b] =
                    f2bf(acc[mt][nt][reg] + bv);
            }
        }
    }
}

// ---------------------------------------------------------------------------
// K3: persistent recurrence. 256 WGs x 256 thr, 1 WG/CU, co-resident.
// NO flags, NO fences: h_hist slots are pre-filled with the bf16 sentinel
// 0x7F7F (unreachable since |h|<1); the data is its own arrival flag.
// All 32 u64 atomic loads for the step are batch-issued (pipelined, one LLC
// round-trip when data already arrived); per-K-slice re-poll only for late
// slices.  Producers publish h via relaxed agent-scope u16 atomic stores
// (LLC write-through -- proven mechanism from the passing flag version).
// Output written directly (fp32 float4) -- no hist32 / emit_out pass.
// ---------------------------------------------------------------------------
__launch_bounds__(256)
__global__ void lstm_rec(const u16* __restrict__ xw2, const u16* __restrict__ whT,
                         u16* __restrict__ h_hist, float* __restrict__ out,
                         float* __restrict__ c_buf, const int Tc, const int t0)
{
    const int w = blockIdx.x;
    const int tid = threadIdx.x;
    const int wave = tid >> 6, lane = tid & 63;
    const int quad = lane >> 4, c16 = lane & 15;
    const int u0 = w << 2;

    // persistent B fragments: local col c16 = q*4+r -> WhT row q*1024+u0+r,
    // wave handles K slice [256*wave, 256*wave+256)
    bf16x8 Breg[8];
    {
        const int q = c16 >> 2, r = c16 & 3;
        const u16* bp = whT + (size_t)(q * 1024 + u0 + r) * 1024 + wave * 256 + quad * 8;
        #pragma unroll
        for (int ks = 0; ks < 8; ++ks) Breg[ks] = *(const bf16x8*)(bp + ks * 32);
    }

    const int eb = tid & 31, eu = tid >> 5;  // epilogue (batch, unit) for tid<128
    float cst = 0.f;
    if (tid < 128) cst = c_buf[eb * 1024 + u0 + eu];

    __shared__ float red[4][32][17];
    __shared__ u16 xbuf[512];
    __shared__ __align__(16) float hsh[32][4];

    const int hrow = (w >> 1) * 32;   // k-packed octet-row base for publish
    const int sub  = (w & 1) << 2;

    // prefetch gate block for t=0 (one coalesced dword per thread)
    unsigned int xd = ((const unsigned int*)(xw2 + (size_t)w * 512))[tid];

    for (int t = 0; t < Tc; ++t) {
        const u16* hsrc = h_hist + (size_t)t * 32768;

        // ---- batch-issue all 32 sentinel-guarded loads (pipelined) ----
        u64 x0[8], x1[8], x2[8], x3[8];
        #pragma unroll
        for (int ks = 0; ks < 8; ++ks) {
            const int octet = wave * 32 + ks * 4 + quad;
            const u64* q0 = (const u64*)(hsrc + (octet * 32 + c16) * 8);
            const u64* q1 = (const u64*)(hsrc + (octet * 32 + 16 + c16) * 8);
            x0[ks] = __hip_atomic_load(q0,     __ATOMIC_RELAXED, __HIP_MEMORY_SCOPE_AGENT);
            x1[ks] = __hip_atomic_load(q0 + 1, __ATOMIC_RELAXED, __HIP_MEMORY_SCOPE_AGENT);
            x2[ks] = __hip_atomic_load(q1,     __ATOMIC_RELAXED, __HIP_MEMORY_SCOPE_AGENT);
            x3[ks] = __hip_atomic_load(q1 + 1, __ATOMIC_RELAXED, __HIP_MEMORY_SCOPE_AGENT);
        }

        f32x4 acc0 = (f32x4){0.f, 0.f, 0.f, 0.f};
        f32x4 acc1 = (f32x4){0.f, 0.f, 0.f, 0.f};
        #pragma unroll
        for (int ks = 0; ks < 8; ++ks) {
            const int octet = wave * 32 + ks * 4 + quad;
            const u64* q0 = (const u64*)(hsrc + (octet * 32 + c16) * 8);
            const u64* q1 = (const u64*)(hsrc + (octet * 32 + 16 + c16) * 8);
            while (bad64(x0[ks]) | bad64(x1[ks]) | bad64(x2[ks]) | bad64(x3[ks])) {
                __builtin_amdgcn_s_sleep(1);
                x0[ks] = __hip_atomic_load(q0,     __ATOMIC_RELAXED, __HIP_MEMORY_SCOPE_AGENT);
                x1[ks] = __hip_atomic_load(q0 + 1, __ATOMIC_RELAXED, __HIP_MEMORY_SCOPE_AGENT);
                x2[ks] = __hip_atomic_load(q1,     __ATOMIC_RELAXED, __HIP_MEMORY_SCOPE_AGENT);
                x3[ks] = __hip_atomic_load(q1 + 1, __ATOMIC_RELAXED, __HIP_MEMORY_SCOPE_AGENT);
            }
            union { u64 d[2]; bf16x8 v; } ua, ub;
            ua.d[0] = x0[ks]; ua.d[1] = x1[ks];
            ub.d[0] = x2[ks]; ub.d[1] = x3[ks];
            acc0 = __builtin_amdgcn_mfma_f32_16x16x32_bf16(ua.v, Breg[ks], acc0, 0, 0, 0);
            acc1 = __builtin_amdgcn_mfma_f32_16x16x32_bf16(ub.v, Breg[ks], acc1, 0, 0, 0);
        }

        // prefetch next step's gate block (completes while we wait next step)
        unsigned int xd_next = 0;
        if (t + 1 < Tc)
            xd_next = ((const unsigned int*)(xw2 + ((size_t)(t + 1) * 256 + w) * 512))[tid];

        // K-split partials -> LDS (C layout: col=c16, row=quad*4+reg)
        #pragma unroll
        for (int reg = 0; reg < 4; ++reg) {
            red[wave][quad * 4 + reg][c16] = acc0[reg];
            red[wave][16 + quad * 4 + reg][c16] = acc1[reg];
        }
        ((unsigned int*)xbuf)[tid] = xd;
        __syncthreads();

        if (tid < 128) {
            float z[4];
            #pragma unroll
            for (int q = 0; q < 4; ++q) {
                const int c = (q << 2) + eu;
                z[q] = red[0][eb][c] + red[1][eb][c] + red[2][eb][c] + red[3][eb][c]
                     + bf2f(xbuf[q * 128 + eu * 32 + eb]);
            }
            const float ig = sigm(z[0]);
            const float fg = sigm(z[1]);
            const float gg = tanh_fast(z[2]);
            const float og = sigm(z[3]);
            cst = fg * cst + ig * gg;
            const float h = og * tanh_fast(cst);
            // publish bf16 h slice, k-packed, write-through to LLC: the store
            // itself clears the sentinel => consumers need no flag, no fence.
            u16* dst = h_hist + (size_t)(t + 1) * 32768 + (size_t)(hrow + eb) * 8 + sub + eu;
            __hip_atomic_store(dst, f2bf(h), __ATOMIC_RELAXED, __HIP_MEMORY_SCOPE_AGENT);
            hsh[eb][eu] = h;
        }
        __syncthreads();
        // direct fp32 output store, off the critical path (after publish)
        if (tid < 32)
            *(float4*)(out + ((size_t)tid * 2048 + t0 + t) * 1024 + u0) =
                *(const float4*)hsh[tid];
        xd = xd_next;
    }
    if (tid < 128) c_buf[eb * 1024 + u0 + eu] = cst;
}

// ---------------------------------------------------------------------------
extern "C" void kernel_launch(void* const* d_in, const int* in_sizes, int n_in,
                              void* d_out, int out_size, void* d_ws, size_t ws_size,
                              hipStream_t stream)
{
    const float* inp  = (const float*)d_in[0];
    const float* Wi   = (const float*)d_in[1];
    const float* Wh   = (const float*)d_in[2];
    const float* bias = (const float*)d_in[3];
    float* out = (float*)d_out;

    char* ws = (char*)d_ws;
    auto alignup = [](size_t x) { return (x + 255) & ~(size_t)255; };

    size_t off = 0;
    const size_t c_off    = off; off = alignup(off + (size_t)32 * 1024 * 4);
    const size_t wiT_off  = off; off = alignup(off + (size_t)4096 * 1024 * 2);
    const size_t whT_off  = off; off = alignup(off + (size_t)4096 * 1024 * 2);
    const size_t fixed_end = off;

    // choose largest T-chunk that fits the workspace
    int Tc = 16;
    const int cands[8] = {2048, 1024, 512, 256, 128, 64, 32, 16};
    for (int i = 0; i < 8; ++i) {
        const int c = cands[i];
        size_t need = fixed_end;
        need = alignup(need + (size_t)c * 32 * 1024 * 2);     // A_bf
        need = alignup(need + (size_t)c * 32 * 4096 * 2);     // xw2
        need = alignup(need + ((size_t)c + 1) * 65536);       // h_hist
        if (need <= ws_size) { Tc = c; break; }
    }
    const size_t a_off   = fixed_end;
    const size_t xw_off  = alignup(a_off  + (size_t)Tc * 32 * 1024 * 2);
    const size_t hh_off  = alignup(xw_off + (size_t)Tc * 32 * 4096 * 2);

    u16*  WiT    = (u16*)(ws + wiT_off);
    u16*  WhT    = (u16*)(ws + whT_off);
    u16*  A_bf   = (u16*)(ws + a_off);
    u16*  xwp    = (u16*)(ws + xw_off);
    u16*  h_hist = (u16*)(ws + hh_off);
    float* c_buf  = (float*)(ws + c_off);

    // one-time weight prep + state init
    transpose_w<<<dim3(128, 32), dim3(32, 8), 0, stream>>>(Wi, WiT);
    transpose_w<<<dim3(128, 32), dim3(32, 8), 0, stream>>>(Wh, WhT);
    hipMemsetAsync(ws + c_off, 0, (size_t)32 * 1024 * 4, stream);
    hipMemsetAsync(ws + hh_off, 0, 65536, stream);   // slot 0: initial h = 0

    const int nchunk = 2048 / Tc;
    for (int c = 0; c < nchunk; ++c) {
        const int t0 = c * Tc;
        convert_inputs<<<Tc * 32, 256, 0, stream>>>(inp, A_bf, t0);
        gemm_xw<<<(Tc * 32 / 128) * 32, 256, 0, stream>>>(A_bf, WiT, bias, xwp);
        // fill slots 1..Tc with the arrival sentinel 0x7F7F
        hipMemsetAsync(ws + hh_off + 65536, 0x7F, (size_t)Tc * 65536, stream);
        lstm_rec<<<256, 256, 0, stream>>>(xwp, WhT, h_hist, out, c_buf, Tc, t0);
        if (c + 1 < nchunk) {
            hipMemcpyAsync(h_hist, h_hist + (size_t)Tc * 32768, 65536,
                           hipMemcpyDeviceToDevice, stream);
        }
    }
}

// Round 3
// 11963.702 us; speedup vs baseline: 2.9660x; 1.1323x over previous
//
#include <hip/hip_runtime.h>
#include <stdint.h>

typedef short bf16x8 __attribute__((ext_vector_type(8)));
typedef float f32x4 __attribute__((ext_vector_type(4)));
typedef int i32x4 __attribute__((ext_vector_type(4)));
typedef unsigned short u16;
typedef unsigned long long u64;

__device__ __forceinline__ u16 f2bf(float f) {
    unsigned int u = __float_as_uint(f);
    u = (u + 0x7FFFu + ((u >> 16) & 1u)) >> 16;
    return (u16)u;
}
__device__ __forceinline__ float bf2f(u16 h) {
    return __uint_as_float(((unsigned int)h) << 16);
}
__device__ __forceinline__ float sigm(float x) { return 1.f / (1.f + __expf(-x)); }
__device__ __forceinline__ float tanh_fast(float x) {
    return 1.f - 2.f / (__expf(2.f * x) + 1.f);
}
// nonzero iff any u16 half of x equals the 0x7F7F sentinel (|h|<1 => unreachable)
__device__ __forceinline__ unsigned bad16(unsigned x) {
    x ^= 0x7F7F7F7Fu;
    return (x - 0x00010001u) & ~x & 0x80008000u;
}
__device__ __forceinline__ unsigned bad4(i32x4 v) {
    return bad16((unsigned)v.x) | bad16((unsigned)v.y) |
           bad16((unsigned)v.z) | bad16((unsigned)v.w);
}
// 16B LLC-coherent load, same cache-bypass path (sc1) the compiler emits for
// agent-scope atomic loads (HW-proven by the passing round-2 kernel), but
// 2x wider and line-coalesced by the vector memory path.
// NOTE: result is NOT ready until an explicit s_waitcnt vmcnt(0)!
__device__ __forceinline__ i32x4 llc_load16(const u16* p) {
    i32x4 r;
    asm volatile("global_load_dwordx4 %0, %1, off sc1" : "=v"(r) : "v"(p));
    return r;
}
__device__ __forceinline__ void vm_wait0() {
    asm volatile("s_waitcnt vmcnt(0)" ::: "memory");
    __builtin_amdgcn_sched_barrier(0);
}

// ---------------------------------------------------------------------------
// K0: transpose fp32 [1024][4096] weight -> bf16 [4096][1024] (K-contiguous)
// ---------------------------------------------------------------------------
__global__ void transpose_w(const float* __restrict__ src, u16* __restrict__ dst)
{
    __shared__ float tile[32][33];
    const int gx = blockIdx.x;   // over 4096/32
    const int gy = blockIdx.y;   // over 1024/32
    const int tx = threadIdx.x;  // 0..31
    const int ty = threadIdx.y;  // 0..7
    #pragma unroll
    for (int i = 0; i < 4; ++i) {
        const int row = gy * 32 + ty + i * 8;
        tile[ty + i * 8][tx] = src[(size_t)row * 4096 + gx * 32 + tx];
    }
    __syncthreads();
    #pragma unroll
    for (int i = 0; i < 4; ++i) {
        const int row = gx * 32 + ty + i * 8;
        dst[(size_t)row * 1024 + gy * 32 + tx] = f2bf(tile[tx][ty + i * 8]);
    }
}

// ---------------------------------------------------------------------------
// K1: convert input chunk fp32 [B][T][D] -> bf16 rows r = t_local*32 + b
// ---------------------------------------------------------------------------
__global__ void convert_inputs(const float* __restrict__ in, u16* __restrict__ A, const int t0)
{
    const int r = blockIdx.x;          // t*32 + b
    const int t = r >> 5, b = r & 31;
    const int d = threadIdx.x << 2;
    const float4 v = *(const float4*)(in + ((size_t)b * 2048 + t0 + t) * 1024 + d);
    ushort4 o = make_ushort4(f2bf(v.x), f2bf(v.y), f2bf(v.z), f2bf(v.w));
    *(ushort4*)(A + (size_t)r * 1024 + d) = o;
}

// ---------------------------------------------------------------------------
// K2: xw2[t][w][q][eu][eb] = sum_k A[r][k] * WiT[g][k] + bias[g]  (bf16)
// 128x128 tile, BK=32, 4 waves each 64x64, mfma 16x16x32 bf16
// ---------------------------------------------------------------------------
__launch_bounds__(256)
__global__ void gemm_xw(const u16* __restrict__ A, const u16* __restrict__ B,
                        const float* __restrict__ bias, u16* __restrict__ C)
{
    __shared__ u16 As[128 * 32];
    __shared__ u16 Bs[128 * 32];
    const int bm = blockIdx.x >> 5;
    const int bn = blockIdx.x & 31;
    const int tid = threadIdx.x;
    const int wave = tid >> 6, lane = tid & 63;
    const int wr = wave >> 1, wc = wave & 1;
    const int c16 = lane & 15, quad = lane >> 4;

    f32x4 acc[4][4];
    #pragma unroll
    for (int i = 0; i < 4; ++i)
        #pragma unroll
        for (int j = 0; j < 4; ++j) acc[i][j] = (f32x4){0.f, 0.f, 0.f, 0.f};

    const int srow = tid >> 1;
    const int scol = (tid & 1) << 4;
    const u16* Ag = A + (size_t)(bm * 128 + srow) * 1024 + scol;
    const u16* Bg = B + (size_t)(bn * 128 + srow) * 1024 + scol;
    uint4* AsW = (uint4*)(As + srow * 32 + scol);
    uint4* BsW = (uint4*)(Bs + srow * 32 + scol);

    for (int kt = 0; kt < 32; ++kt) {
        const uint4* ag = (const uint4*)(Ag + kt * 32);
        const uint4* bg = (const uint4*)(Bg + kt * 32);
        const uint4 a0 = ag[0], a1 = ag[1];
        const uint4 b0 = bg[0], b1 = bg[1];
        __syncthreads();
        AsW[0] = a0; AsW[1] = a1;
        BsW[0] = b0; BsW[1] = b1;
        __syncthreads();
        bf16x8 af[4], bfr[4];
        #pragma unroll
        for (int mt = 0; mt < 4; ++mt)
            af[mt] = *(const bf16x8*)(As + (wr * 64 + mt * 16 + c16) * 32 + quad * 8);
        #pragma unroll
        for (int nt = 0; nt < 4; ++nt)
            bfr[nt] = *(const bf16x8*)(Bs + (wc * 64 + nt * 16 + c16) * 32 + quad * 8);
        #pragma unroll
        for (int mt = 0; mt < 4; ++mt)
            #pragma unroll
            for (int nt = 0; nt < 4; ++nt)
                acc[mt][nt] = __builtin_amdgcn_mfma_f32_16x16x32_bf16(af[mt], bfr[nt], acc[mt][nt], 0, 0, 0);
    }
    #pragma unroll
    for (int nt = 0; nt < 4; ++nt) {
        const int g = bn * 128 + wc * 64 + nt * 16 + c16;
        const float bv = bias[g];
        const int q  = g >> 10;
        const int u  = g & 1023;
        const int w2 = u >> 2, eu = u & 3;
        #pragma unroll
        for (int mt = 0; mt < 4; ++mt) {
            const int r0 = bm * 128 + wr * 64 + mt * 16 + quad * 4;
            #pragma unroll
            for (int reg = 0; reg < 4; ++reg) {
                const int r = r0 + reg;
                const int t = r >> 5, b = r & 31;
                C[(size_t)(t * 256 + w2) * 512 + q * 128 + eu * 32 + b] =
                    f2bf(acc[mt][nt][reg] + bv);
            }
        }
    }
}

// ---------------------------------------------------------------------------
// K3: persistent recurrence. 256 WGs x 256 thr, 1 WG/CU, co-resident.
// Sentinel dataflow (0x7F7F, unreachable since |h|<1): the data is its own
// arrival flag; no fences, no flag round-trips.
//   - consumer polls: 16B global_load_dwordx4 sc1 (line-coalesced, batch-
//     issued, explicit vmcnt) -- 4-8x fewer LLC transactions than u64 atomics
//   - producer publish: one packed u64 agent atomic store per batch row
//     (32 stores/WG instead of 128 u16) -- each checked u64 is written whole
// ---------------------------------------------------------------------------
__launch_bounds__(256)
__global__ void lstm_rec(const u16* __restrict__ xw2, const u16* __restrict__ whT,
                         u16* __restrict__ h_hist, float* __restrict__ out,
                         float* __restrict__ c_buf, const int Tc, const int t0)
{
    const int w = blockIdx.x;
    const int tid = threadIdx.x;
    const int wave = tid >> 6, lane = tid & 63;
    const int quad = lane >> 4, c16 = lane & 15;
    const int u0 = w << 2;

    // persistent B fragments: local col c16 = q*4+r -> WhT row q*1024+u0+r,
    // wave handles K slice [256*wave, 256*wave+256)
    bf16x8 Breg[8];
    {
        const int q = c16 >> 2, r = c16 & 3;
        const u16* bp = whT + (size_t)(q * 1024 + u0 + r) * 1024 + wave * 256 + quad * 8;
        #pragma unroll
        for (int ks = 0; ks < 8; ++ks) Breg[ks] = *(const bf16x8*)(bp + ks * 32);
    }

    const int eb = tid & 31, eu = tid >> 5;  // epilogue (batch, unit) for tid<128
    float cst = 0.f;
    if (tid < 128) cst = c_buf[eb * 1024 + u0 + eu];

    __shared__ float red[4][32][17];
    __shared__ u16 xbuf[512];
    __shared__ __align__(16) float hsh[32][4];
    __shared__ __align__(8)  u16 hbf[32][4];

    const int hrow = (w >> 1) * 32;   // k-packed octet-row base for publish
    const int sub  = (w & 1) << 2;

    // prefetch gate block for t=0 (one coalesced dword per thread)
    unsigned int xd = ((const unsigned int*)(xw2 + (size_t)w * 512))[tid];

    for (int t = 0; t < Tc; ++t) {
        const u16* hsrc = h_hist + (size_t)t * 32768;

        // ---- batch-issue all 16 sentinel-guarded 16B loads (pipelined) ----
        i32x4 xa[8], xb[8];
        #pragma unroll
        for (int ks = 0; ks < 8; ++ks) {
            const int octet = wave * 32 + ks * 4 + quad;
            xa[ks] = llc_load16(hsrc + (octet * 32 + c16) * 8);
            xb[ks] = llc_load16(hsrc + (octet * 32 + 16 + c16) * 8);
        }
        vm_wait0();

        f32x4 acc0 = (f32x4){0.f, 0.f, 0.f, 0.f};
        f32x4 acc1 = (f32x4){0.f, 0.f, 0.f, 0.f};
        #pragma unroll
        for (int ks = 0; ks < 8; ++ks) {
            const int octet = wave * 32 + ks * 4 + quad;
            while (bad4(xa[ks]) | bad4(xb[ks])) {
                __builtin_amdgcn_s_sleep(1);
                xa[ks] = llc_load16(hsrc + (octet * 32 + c16) * 8);
                xb[ks] = llc_load16(hsrc + (octet * 32 + 16 + c16) * 8);
                vm_wait0();
            }
            union { i32x4 i; bf16x8 v; } ua, ub;
            ua.i = xa[ks];
            ub.i = xb[ks];
            acc0 = __builtin_amdgcn_mfma_f32_16x16x32_bf16(ua.v, Breg[ks], acc0, 0, 0, 0);
            acc1 = __builtin_amdgcn_mfma_f32_16x16x32_bf16(ub.v, Breg[ks], acc1, 0, 0, 0);
        }

        // prefetch next step's gate block (completes while we wait next step)
        unsigned int xd_next = 0;
        if (t + 1 < Tc)
            xd_next = ((const unsigned int*)(xw2 + ((size_t)(t + 1) * 256 + w) * 512))[tid];

        // K-split partials -> LDS (C layout: col=c16, row=quad*4+reg)
        #pragma unroll
        for (int reg = 0; reg < 4; ++reg) {
            red[wave][quad * 4 + reg][c16] = acc0[reg];
            red[wave][16 + quad * 4 + reg][c16] = acc1[reg];
        }
        ((unsigned int*)xbuf)[tid] = xd;
        __syncthreads();

        if (tid < 128) {
            float z[4];
            #pragma unroll
            for (int q = 0; q < 4; ++q) {
                const int c = (q << 2) + eu;
                z[q] = red[0][eb][c] + red[1][eb][c] + red[2][eb][c] + red[3][eb][c]
                     + bf2f(xbuf[q * 128 + eu * 32 + eb]);
            }
            const float ig = sigm(z[0]);
            const float fg = sigm(z[1]);
            const float gg = tanh_fast(z[2]);
            const float og = sigm(z[3]);
            cst = fg * cst + ig * gg;
            const float h = og * tanh_fast(cst);
            hbf[eb][eu] = f2bf(h);
            hsh[eb][eu] = h;
        }
        __syncthreads();
        if (tid < 32) {
            // publish packed u64 (4 bf16 h) per batch row: one store, whole
            // quantum -- the consumer's 16B sentinel check sees it atomically.
            const u64 pk = *(const u64*)hbf[tid];
            u64* dst = (u64*)(h_hist + (size_t)(t + 1) * 32768 + (size_t)(hrow + tid) * 8 + sub);
            __hip_atomic_store(dst, pk, __ATOMIC_RELAXED, __HIP_MEMORY_SCOPE_AGENT);
            // direct fp32 output store, off the critical path (after publish)
            *(float4*)(out + ((size_t)tid * 2048 + t0 + t) * 1024 + u0) =
                *(const float4*)hsh[tid];
        }
        xd = xd_next;
    }
    if (tid < 128) c_buf[eb * 1024 + u0 + eu] = cst;
}

// ---------------------------------------------------------------------------
extern "C" void kernel_launch(void* const* d_in, const int* in_sizes, int n_in,
                              void* d_out, int out_size, void* d_ws, size_t ws_size,
                              hipStream_t stream)
{
    const float* inp  = (const float*)d_in[0];
    const float* Wi   = (const float*)d_in[1];
    const float* Wh   = (const float*)d_in[2];
    const float* bias = (const float*)d_in[3];
    float* out = (float*)d_out;

    char* ws = (char*)d_ws;
    auto alignup = [](size_t x) { return (x + 255) & ~(size_t)255; };

    size_t off = 0;
    const size_t c_off    = off; off = alignup(off + (size_t)32 * 1024 * 4);
    const size_t wiT_off  = off; off = alignup(off + (size_t)4096 * 1024 * 2);
    const size_t whT_off  = off; off = alignup(off + (size_t)4096 * 1024 * 2);
    const size_t fixed_end = off;

    // choose largest T-chunk that fits the workspace
    int Tc = 16;
    const int cands[8] = {2048, 1024, 512, 256, 128, 64, 32, 16};
    for (int i = 0; i < 8; ++i) {
        const int c = cands[i];
        size_t need = fixed_end;
        need = alignup(need + (size_t)c * 32 * 1024 * 2);     // A_bf
        need = alignup(need + (size_t)c * 32 * 4096 * 2);     // xw2
        need = alignup(need + ((size_t)c + 1) * 65536);       // h_hist
        if (need <= ws_size) { Tc = c; break; }
    }
    const size_t a_off   = fixed_end;
    const size_t xw_off  = alignup(a_off  + (size_t)Tc * 32 * 1024 * 2);
    const size_t hh_off  = alignup(xw_off + (size_t)Tc * 32 * 4096 * 2);

    u16*  WiT    = (u16*)(ws + wiT_off);
    u16*  WhT    = (u16*)(ws + whT_off);
    u16*  A_bf   = (u16*)(ws + a_off);
    u16*  xwp    = (u16*)(ws + xw_off);
    u16*  h_hist = (u16*)(ws + hh_off);
    float* c_buf  = (float*)(ws + c_off);

    // one-time weight prep + state init
    transpose_w<<<dim3(128, 32), dim3(32, 8), 0, stream>>>(Wi, WiT);
    transpose_w<<<dim3(128, 32), dim3(32, 8), 0, stream>>>(Wh, WhT);
    hipMemsetAsync(ws + c_off, 0, (size_t)32 * 1024 * 4, stream);
    hipMemsetAsync(ws + hh_off, 0, 65536, stream);   // slot 0: initial h = 0

    const int nchunk = 2048 / Tc;
    for (int c = 0; c < nchunk; ++c) {
        const int t0 = c * Tc;
        convert_inputs<<<Tc * 32, 256, 0, stream>>>(inp, A_bf, t0);
        gemm_xw<<<(Tc * 32 / 128) * 32, 256, 0, stream>>>(A_bf, WiT, bias, xwp);
        // fill slots 1..Tc with the arrival sentinel 0x7F7F
        hipMemsetAsync(ws + hh_off + 65536, 0x7F, (size_t)Tc * 65536, stream);
        lstm_rec<<<256, 256, 0, stream>>>(xwp, WhT, h_hist, out, c_buf, Tc, t0);
        if (c + 1 < nchunk) {
            hipMemcpyAsync(h_hist, h_hist + (size_t)Tc * 32768, 65536,
                           hipMemcpyDeviceToDevice, stream);
        }
    }
}